// Round 1
// baseline (116.134 us; speedup 1.0000x reference)
//
#include <hip/hip_runtime.h>
#include <math.h>

#define N_PTS 16384
#define TPB 256
#define PQ 4                     // queries per thread
#define QPB (TPB * PQ)           // 1024 queries per block
#define NQGROUP (2 * N_PTS / QPB) // 32 query groups (pred + gt sides)
#define NCHUNK 16                // target chunks -> 512 blocks total
#define TC (N_PTS / NCHUNK)      // 1024 targets per chunk
#define LT 256                   // LDS tile size (targets)

// ws layout:
//   [0 .. 255]                          : float acc[2] {sumDist, sumColor} (+pad)
//   [256 .. 256+2*N*16)                 : float4 predQ[N], gtQ[N]  (x,y,z, 0.5*|xyz|^2)
//   [256+2*N*16 .. +2*N*4)              : unsigned minKeys[2N]

__global__ void prep_kernel(const float* __restrict__ pred,
                            const float* __restrict__ gt,
                            float4* __restrict__ predQ,
                            float4* __restrict__ gtQ,
                            float* __restrict__ acc) {
    int i = blockIdx.x * blockDim.x + threadIdx.x;  // 0..N_PTS-1
    const float2* pr = (const float2*)(pred + (size_t)i * 6);
    float2 a = pr[0], b = pr[1], c = pr[2];
    const float2* gr = (const float2*)(gt + (size_t)i * 6);
    float2 d = gr[0], e = gr[1], f = gr[2];

    float pn = 0.5f * (a.x * a.x + a.y * a.y + b.x * b.x);
    float gn = 0.5f * (d.x * d.x + d.y * d.y + e.x * e.x);
    predQ[i] = make_float4(a.x, a.y, b.x, pn);
    gtQ[i]   = make_float4(d.x, d.y, e.x, gn);

    // color L1 partial: elements 3,4,5 of each row
    float csum = fabsf(b.y - e.y) + fabsf(c.x - f.x) + fabsf(c.y - f.y);
    #pragma unroll
    for (int o = 32; o; o >>= 1) csum += __shfl_down(csum, o);
    if ((threadIdx.x & 63) == 0) atomicAdd(&acc[1], csum);
}

__global__ __launch_bounds__(TPB) void pairs_kernel(const float4* __restrict__ predQ,
                                                    const float4* __restrict__ gtQ,
                                                    unsigned* __restrict__ minKeys) {
    __shared__ float4 tile[LT];
    int bid = blockIdx.x;
    int qg = bid & (NQGROUP - 1);  // 0..31
    int chunk = bid >> 5;          // 0..NCHUNK-1
    int qbase = qg * QPB;          // 0..31744 (global query index base)

    const float4* qArr;
    const float4* tArr;
    int side_off;   // offset of this side's queries in the global query index space
    if (qbase < N_PTS) {
        qArr = predQ; tArr = gtQ; side_off = 0;
    } else {
        qArr = gtQ; tArr = predQ; side_off = N_PTS; qbase -= N_PTS;
    }

    int tid = threadIdx.x;
    float4 q[PQ];
    float fm[PQ];
    #pragma unroll
    for (int k = 0; k < PQ; k++) {
        q[k] = qArr[qbase + tid + k * TPB];
        fm[k] = 3.0e38f;
    }

    int tbase = chunk * TC;
    for (int t0 = 0; t0 < TC; t0 += LT) {
        __syncthreads();
        tile[tid] = tArr[tbase + t0 + tid];
        __syncthreads();
        #pragma unroll 8
        for (int j = 0; j < LT; j++) {
            float4 g = tile[j];
            #pragma unroll
            for (int k = 0; k < PQ; k++) {
                float f = __builtin_fmaf(-q[k].z, g.z, g.w);
                f = __builtin_fmaf(-q[k].y, g.y, f);
                f = __builtin_fmaf(-q[k].x, g.x, f);
                fm[k] = fminf(fm[k], f);
            }
        }
    }

    #pragma unroll
    for (int k = 0; k < PQ; k++) {
        unsigned bits = __float_as_uint(fm[k]);
        unsigned key = (bits & 0x80000000u) ? ~bits : (bits | 0x80000000u);
        atomicMin(&minKeys[side_off + qbase + tid + k * TPB], key);
    }
}

__global__ void finalize_kernel(const float4* __restrict__ predQ,
                                const float4* __restrict__ gtQ,
                                const unsigned* __restrict__ minKeys,
                                float* __restrict__ acc) {
    int i = blockIdx.x * blockDim.x + threadIdx.x;  // 0..2N-1
    unsigned key = minKeys[i];
    unsigned bits = (key & 0x80000000u) ? (key ^ 0x80000000u) : ~key;
    float f = __uint_as_float(bits);
    float4 q = (i < N_PTS) ? predQ[i] : gtQ[i - N_PTS];
    float sq = 2.0f * (f + q.w);
    float dmin = sqrtf(fmaxf(sq, 0.0f));
    #pragma unroll
    for (int o = 32; o; o >>= 1) dmin += __shfl_down(dmin, o);
    if ((threadIdx.x & 63) == 0) atomicAdd(&acc[0], dmin);
}

__global__ void finish_kernel(const float* __restrict__ acc, float* __restrict__ out) {
    // chamfer = (sum of all 2N min-dists) / N ; color = sumColor / (3N)
    out[0] = acc[0] * (1.0f / N_PTS) + 0.1f * acc[1] * (1.0f / (3.0f * N_PTS));
}

extern "C" void kernel_launch(void* const* d_in, const int* in_sizes, int n_in,
                              void* d_out, int out_size, void* d_ws, size_t ws_size,
                              hipStream_t stream) {
    const float* pred = (const float*)d_in[0];
    const float* gt = (const float*)d_in[1];
    char* base = (char*)d_ws;
    float* acc = (float*)base;
    float4* predQ = (float4*)(base + 256);
    float4* gtQ = predQ + N_PTS;
    unsigned* minKeys = (unsigned*)(base + 256 + (size_t)2 * N_PTS * sizeof(float4));
    float* out = (float*)d_out;

    hipMemsetAsync(acc, 0, 2 * sizeof(float), stream);
    hipMemsetAsync(minKeys, 0xFF, (size_t)2 * N_PTS * sizeof(unsigned), stream);

    prep_kernel<<<N_PTS / TPB, TPB, 0, stream>>>(pred, gt, predQ, gtQ, acc);
    pairs_kernel<<<NQGROUP * NCHUNK, TPB, 0, stream>>>(predQ, gtQ, minKeys);
    finalize_kernel<<<2 * N_PTS / TPB, TPB, 0, stream>>>(predQ, gtQ, minKeys, acc);
    finish_kernel<<<1, 1, 0, stream>>>(acc, out);
}

// Round 3
// 99.614 us; speedup vs baseline: 1.1658x; 1.1658x over previous
//
#include <hip/hip_runtime.h>
#include <math.h>

#define N_PTS 16384
#define TPB 256
#define PQ 4                      // queries per thread
#define QPB (TPB * PQ)            // 1024 queries per block
#define NQG (2 * N_PTS / QPB)     // 32 query groups (both sides)

typedef float v2f __attribute__((ext_vector_type(2)));
typedef float v4f __attribute__((ext_vector_type(4)));

// ws layout:
//   [0 .. 4KB)         : float partials[1024]  (512 dist-wave-sums, 512 color-wave-sums)
//   [4KB .. )          : float minPart[NCHUNK][2*N_PTS]
//
// pairs: each block = (query group qg, target chunk c). Queries held in regs
// (negated, broadcast into packed pairs), whole target chunk staged once in
// LDS as pair-interleaved SoA: tileA[t]={x0,x1,y0,y1}, tileB[t]={z0,z1,w0,w1}
// with w = 0.5*|xyz|^2. Inner op per 2 targets per query:
//   3x v_pk_fma_f32 + 1x v_min3_f32  (f = 0.5|g|^2 - p.g, monotone in dist)

template <int NCHUNK>
__global__ __launch_bounds__(TPB) void pairs_kernel(const float* __restrict__ pred,
                                                    const float* __restrict__ gt,
                                                    float* __restrict__ minPart) {
    constexpr int TC = N_PTS / NCHUNK;   // targets per chunk
    __shared__ v4f tileA[TC / 2];
    __shared__ v4f tileB[TC / 2];

    int bid = blockIdx.x;
    int qg = bid % NQG;
    int chunk = bid / NQG;
    int gq0 = qg * QPB;                  // global query base in [0, 2N)

    const float* qRaw;
    const float* tRaw;
    int qbase;
    if (gq0 < N_PTS) { qRaw = pred; tRaw = gt; qbase = gq0; }
    else             { qRaw = gt; tRaw = pred; qbase = gq0 - N_PTS; }

    int tid = threadIdx.x;
    int tbase = chunk * TC;

    // ---- stage target chunk into LDS (pair-interleaved SoA) ----
    // two consecutive rows = 48B = three aligned float4s (48 = 3*16).
    for (int p = tid; p < TC / 2; p += TPB) {
        const v4f* r = (const v4f*)(tRaw + (size_t)(tbase + 2 * p) * 6);
        v4f r0 = r[0];                   // x0 y0 z0 c
        v4f r1 = r[1];                   // c  c  x1 y1
        v4f r2 = r[2];                   // z1 c  c  c
        float x0 = r0.x, y0 = r0.y, z0 = r0.z;
        float x1 = r1.z, y1 = r1.w, z1 = r2.x;
        float w0 = 0.5f * (x0 * x0 + y0 * y0 + z0 * z0);
        float w1 = 0.5f * (x1 * x1 + y1 * y1 + z1 * z1);
        tileA[p] = (v4f){x0, x1, y0, y1};
        tileB[p] = (v4f){z0, z1, w0, w1};
    }

    // ---- load queries into regs (negated, broadcast pairs) ----
    v2f nqx[PQ], nqy[PQ], nqz[PQ];
    float fm[PQ];
#pragma unroll
    for (int k = 0; k < PQ; k++) {
        int qi = qbase + tid + k * TPB;
        const float2* r = (const float2*)(qRaw + (size_t)qi * 6);
        float2 a = r[0];                 // x, y
        float z = r[1].x;                // z
        nqx[k] = (v2f){-a.x, -a.x};
        nqy[k] = (v2f){-a.y, -a.y};
        nqz[k] = (v2f){-z, -z};
        fm[k] = 3.0e38f;
    }
    __syncthreads();

    // ---- main loop: TC/2 target pairs, broadcast LDS reads ----
#pragma unroll 4
    for (int t = 0; t < TC / 2; t++) {
        v4f A = tileA[t];
        v4f B = tileB[t];
        v2f X = A.xy, Y = A.zw, Z = B.xy, W = B.zw;
#pragma unroll
        for (int k = 0; k < PQ; k++) {
            v2f f = __builtin_elementwise_fma(nqz[k], Z, W);
            f = __builtin_elementwise_fma(nqy[k], Y, f);
            f = __builtin_elementwise_fma(nqx[k], X, f);
            fm[k] = fminf(fm[k], fminf(f.x, f.y));   // hope: v_min3_f32
        }
    }

    float* dst = minPart + (size_t)chunk * (2 * N_PTS) + gq0;
#pragma unroll
    for (int k = 0; k < PQ; k++) dst[tid + k * TPB] = fm[k];
}

template <int NCHUNK>
__global__ void finalize_kernel(const float* __restrict__ pred,
                                const float* __restrict__ gt,
                                const float* __restrict__ minPart,
                                float* __restrict__ partials) {
    int i = blockIdx.x * blockDim.x + threadIdx.x;   // 0..2N-1
    float f = minPart[i];
#pragma unroll
    for (int c = 1; c < NCHUNK; c++) f = fminf(f, minPart[(size_t)c * (2 * N_PTS) + i]);

    int qi = (i < N_PTS) ? i : i - N_PTS;
    const float* qr = (i < N_PTS) ? pred : gt;
    const float2* r = (const float2*)(qr + (size_t)qi * 6);
    float2 a = r[0], b = r[1];
    float n = 0.5f * (a.x * a.x + a.y * a.y + b.x * b.x);
    float d = sqrtf(fmaxf(2.0f * (f + n), 0.0f));

    float csum = 0.0f;
    if (i < N_PTS) {   // color L1, one thread per point pair
        float2 c1 = r[2];
        const float2* g = (const float2*)(gt + (size_t)qi * 6);
        float2 gb = g[1], gc = g[2];
        csum = fabsf(b.y - gb.y) + fabsf(c1.x - gc.x) + fabsf(c1.y - gc.y);
    }

#pragma unroll
    for (int o = 32; o; o >>= 1) { d += __shfl_down(d, o); csum += __shfl_down(csum, o); }
    if ((threadIdx.x & 63) == 0) {
        int w = (blockIdx.x * blockDim.x + threadIdx.x) >> 6;
        partials[w] = d;
        partials[512 + w] = csum;
    }
}

__global__ void finish_kernel(const float* __restrict__ partials, float* __restrict__ out) {
    __shared__ float sd[8], sc[8];
    int tid = threadIdx.x;   // 512 threads
    float d = partials[tid], c = partials[512 + tid];
#pragma unroll
    for (int o = 32; o; o >>= 1) { d += __shfl_down(d, o); c += __shfl_down(c, o); }
    if ((tid & 63) == 0) { sd[tid >> 6] = d; sc[tid >> 6] = c; }
    __syncthreads();
    if (tid == 0) {
        float D = 0.f, C = 0.f;
#pragma unroll
        for (int w = 0; w < 8; w++) { D += sd[w]; C += sc[w]; }
        out[0] = D * (1.0f / N_PTS) + 0.1f * C * (1.0f / (3.0f * N_PTS));
    }
}

extern "C" void kernel_launch(void* const* d_in, const int* in_sizes, int n_in,
                              void* d_out, int out_size, void* d_ws, size_t ws_size,
                              hipStream_t stream) {
    const float* pred = (const float*)d_in[0];
    const float* gt = (const float*)d_in[1];
    char* base = (char*)d_ws;
    float* partials = (float*)base;
    float* minPart = (float*)(base + 4096);
    float* out = (float*)d_out;

    size_t need32 = 4096 + (size_t)32 * 2 * N_PTS * 4;
    size_t need16 = 4096 + (size_t)16 * 2 * N_PTS * 4;

    if (ws_size >= need32) {
        pairs_kernel<32><<<NQG * 32, TPB, 0, stream>>>(pred, gt, minPart);
        finalize_kernel<32><<<2 * N_PTS / TPB, TPB, 0, stream>>>(pred, gt, minPart, partials);
    } else if (ws_size >= need16) {
        pairs_kernel<16><<<NQG * 16, TPB, 0, stream>>>(pred, gt, minPart);
        finalize_kernel<16><<<2 * N_PTS / TPB, TPB, 0, stream>>>(pred, gt, minPart, partials);
    } else {
        pairs_kernel<8><<<NQG * 8, TPB, 0, stream>>>(pred, gt, minPart);
        finalize_kernel<8><<<2 * N_PTS / TPB, TPB, 0, stream>>>(pred, gt, minPart, partials);
    }
    finish_kernel<<<1, 512, 0, stream>>>(partials, out);
}